// Round 12
// baseline (163.616 us; speedup 1.0000x reference)
//
#include <hip/hip_runtime.h>

#define SLEN 2048
#define EDIM 1024
#define HNUM 16
#define DDIM 64

typedef unsigned short u16;
typedef unsigned int u32;
typedef __attribute__((ext_vector_type(8))) __bf16 bf16x8;
typedef __attribute__((ext_vector_type(2))) __bf16 bf16x2;
typedef __attribute__((ext_vector_type(4))) float f32x4;
typedef __attribute__((ext_vector_type(16))) float f32x16;

__device__ __forceinline__ u16 f2bf(float f) {
  u32 u = __builtin_bit_cast(u32, f);
  u = (u + 0x7fffu + ((u >> 16) & 1u)) >> 16;
  return (u16)u;
}

__device__ __forceinline__ float bf2f(u16 v) {
  u32 u = ((u32)v) << 16;
  return __builtin_bit_cast(float, u);
}

__device__ __forceinline__ u32 packbf(float a, float b) {
  bf16x2 t; t[0] = (__bf16)a; t[1] = (__bf16)b;
  return __builtin_bit_cast(u32, t);
}

__device__ __forceinline__ void gload_lds16(const void* g, void* l) {
  __builtin_amdgcn_global_load_lds(
      (const __attribute__((address_space(1))) void*)g,
      (__attribute__((address_space(3))) void*)l, 16, 0, 0);
}

// XOR swizzle for 128B-row LDS tiles
__device__ __forceinline__ u32 swz(u32 b) { return b ^ (((b >> 7) & 7u) << 4); }

// ---------------- GEMM 64x128 tile, split-K, fused V-transpose ----------------
// MODE 0: bf16=acc+bias; if vtp && col>=2048, store transposed to vtp instead of outp.
// MODE 1: bf16=relu(acc+bias)
// MODE 3: f32 partial (no bias), z=0 -> outp, z=1 -> part1
template<int MODE>
__global__ __launch_bounds__(256, 4) void gemm_bt64(
    const u16* __restrict__ A, const u16* __restrict__ Bt,
    const float* __restrict__ bias, float* __restrict__ part1,
    void* __restrict__ outp, u16* __restrict__ vtp, int M, int N, int lda, int KS)
{
  __shared__ __align__(16) u16 As[64 * 64];    // 8KB
  __shared__ __align__(16) u16 Bs[128 * 64];   // 16KB
  const int t = threadIdx.x;
  const int lane = t & 63, wv = t >> 6;
  const int bm = blockIdx.y * 64, bn = blockIdx.x * 128;
  const int wm = (wv >> 1) * 32, wn = (wv & 1) * 64;
  const int koff = blockIdx.z * KS;
  f32x4 acc[2][4] = {};

  const char* Ab = (const char*)A;
  const char* Bb = (const char*)Bt;

  for (int k0 = koff; k0 < koff + KS; k0 += 64) {
    __syncthreads();
    {
      u32 bp = (u32)t * 16u;
      u32 L = swz(bp);
      u32 row = L >> 7, colb = L & 127u;
      gload_lds16(Ab + ((size_t)(bm + row) * lda + k0) * 2 + colb, (char*)As + bp);
      u32 bp2 = bp + 4096u;
      u32 L2 = swz(bp2);
      u32 row2 = L2 >> 7, colb2 = L2 & 127u;
      gload_lds16(Ab + ((size_t)(bm + row2) * lda + k0) * 2 + colb2, (char*)As + bp2);
    }
#pragma unroll
    for (int j = 0; j < 4; ++j) {
      u32 bp = (u32)t * 16u + (u32)j * 4096u;
      u32 L = swz(bp);
      u32 row = L >> 7, colb = L & 127u;
      gload_lds16(Bb + ((size_t)(bn + row) * lda + k0) * 2 + colb, (char*)Bs + bp);
    }
    __syncthreads();
#pragma unroll
    for (int ks = 0; ks < 2; ++ks) {
      bf16x8 af[2], bfr[4];
#pragma unroll
      for (int i = 0; i < 2; ++i) {
        u32 ra = (u32)(wm + i * 16 + (lane & 15));
        u32 La = (ra << 7) + (u32)ks * 64u + (u32)(lane >> 4) * 16u;
        af[i] = *(const bf16x8*)((const char*)As + (La ^ ((ra & 7u) << 4)));
      }
#pragma unroll
      for (int i = 0; i < 4; ++i) {
        u32 rb = (u32)(wn + i * 16 + (lane & 15));
        u32 Lb = (rb << 7) + (u32)ks * 64u + (u32)(lane >> 4) * 16u;
        bfr[i] = *(const bf16x8*)((const char*)Bs + (Lb ^ ((rb & 7u) << 4)));
      }
#pragma unroll
      for (int mi = 0; mi < 2; ++mi)
#pragma unroll
        for (int ni = 0; ni < 4; ++ni)
          acc[mi][ni] = __builtin_amdgcn_mfma_f32_16x16x32_bf16(af[mi], bfr[ni], acc[mi][ni], 0, 0, 0);
    }
  }

  float* po = (MODE == 3 && blockIdx.z) ? part1 : (float*)outp;
  const int cr = (lane >> 4) * 4, cc = lane & 15;
#pragma unroll
  for (int ni = 0; ni < 4; ++ni) {
    const int colb0 = bn + wn + ni * 16;   // wave-uniform
    const int col = colb0 + cc;
    if (MODE == 0 && vtp != nullptr && colb0 >= 2048) {
      // V columns: store transposed Vt[col-2048][row0..row0+3] (8B aligned)
      const float bvv = bias[col];
      const int vcol = col - 2048;
#pragma unroll
      for (int mi = 0; mi < 2; ++mi) {
        const int row0 = bm + wm + mi * 16 + cr;
        uint2 st;
        st.x = packbf(acc[mi][ni][0] + bvv, acc[mi][ni][1] + bvv);
        st.y = packbf(acc[mi][ni][2] + bvv, acc[mi][ni][3] + bvv);
        *(uint2*)(vtp + (size_t)vcol * SLEN + row0) = st;
      }
    } else {
      const float bvv = (MODE == 3) ? 0.f : bias[col];
#pragma unroll
      for (int mi = 0; mi < 2; ++mi) {
#pragma unroll
        for (int r = 0; r < 4; ++r) {
          const int row = bm + wm + mi * 16 + cr + r;
          float v = acc[mi][ni][r] + bvv;
          const size_t idx = (size_t)row * N + col;
          if constexpr (MODE == 0) ((u16*)outp)[idx] = f2bf(v);
          else if constexpr (MODE == 1) ((u16*)outp)[idx] = f2bf(v > 0.f ? v : 0.f);
          else po[idx] = v;
        }
      }
    }
  }
}

// ---------------- flash attention, 32x32 MFMA, KV-split-3 (R9-proven) ----------------
// Block (qt, h, z): q-rows qt*128..+127 (4 waves x 32), keys: z<2 ? 768 : 512.
// Partials: zp bf16 [bid][128 q][64 d], mlb float2 [bid][128 q]; bid=(h*16+qt)*3+z.
__global__ __launch_bounds__(256, 4) void attn_kernel(
    const u16* __restrict__ qkv, const u16* __restrict__ vt,
    u16* __restrict__ zp, float2* __restrict__ mlb)
{
  __shared__ __align__(16) char lds[32768];  // 2 bufs x (K 8KB + Vt 8KB)
  const int t = threadIdx.x, lane = t & 63;
  const int q31 = lane & 31, hi = lane >> 5;
  const int wv = t >> 6;
  const int h = blockIdx.y;
  const int qrow = blockIdx.x * 128 + wv * 32 + q31;
  const int kt0 = blockIdx.z * 12;
  const int cnt = (blockIdx.z == 2) ? 8 : 12;

  bf16x8 qf[4];
#pragma unroll
  for (int ds = 0; ds < 4; ++ds)
    qf[ds] = *(const bf16x8*)(qkv + (size_t)qrow * 3072 + h * 64 + ds * 16 + hi * 8);

  const char* kgp[2];
  const char* vgp[2];
  u32 ldo[2];
#pragma unroll
  for (int j = 0; j < 2; ++j) {
    u32 bp = (u32)t * 16u + (u32)j * 4096u;
    u32 L = swz(bp);
    u32 row = L >> 7, colb = L & 127u;
    kgp[j] = (const char*)qkv + ((size_t)row * 3072 + 1024 + h * 64) * 2 + colb;
    vgp[j] = (const char*)vt + ((size_t)(h * 64 + row)) * (SLEN * 2) + colb;
    ldo[j] = bp;
  }

  f32x16 zacc[2] = {};   // zacc[dh][reg] = z^T[32*dh + (reg&3)+8*(reg>>2)+4*hi][q31]
  float m = -1e30f, l = 0.f;

  {
    size_t ko = (size_t)kt0 * (64 * 3072 * 2);
    int vo = kt0 * 128;
#pragma unroll
    for (int j = 0; j < 2; ++j) {
      gload_lds16(kgp[j] + ko, lds + ldo[j]);
      gload_lds16(vgp[j] + vo, lds + 8192 + ldo[j]);
    }
  }
  __syncthreads();

  int cur = 0;
  for (int it = 0; it < cnt; ++it) {
    const int kt = kt0 + it;
    if (it + 1 < cnt) {
      char* base = lds + (cur ^ 1) * 16384;
      size_t ko = (size_t)(kt + 1) * (64 * 3072 * 2);
      int vo = (kt + 1) * 128;
#pragma unroll
      for (int j = 0; j < 2; ++j) {
        gload_lds16(kgp[j] + ko, base + ldo[j]);
        gload_lds16(vgp[j] + vo, base + 8192 + ldo[j]);
      }
    }

    const char* Kl = lds + cur * 16384;
    const char* Vl = Kl + 8192;

#pragma unroll
    for (int kh = 0; kh < 2; ++kh) {
      // QK^T swapped: P[kc][q], kc = kh*32 + (reg&3)+8*(reg>>2)+4*hi, q = q31
      f32x16 p = {};
#pragma unroll
      for (int ds = 0; ds < 4; ++ds) {
        u32 rk = (u32)(kh * 32 + q31);
        u32 L = (rk << 7) + (u32)ds * 32u + (u32)hi * 16u;
        bf16x8 kf = *(const bf16x8*)(Kl + (L ^ ((rk & 7u) << 4)));
        p = __builtin_amdgcn_mfma_f32_32x32x16_bf16(kf, qf[ds], p, 0, 0, 0);
      }

      // online softmax (defer-max); max reduce as v_max3 tree
      float a0 = fmaxf(fmaxf(p[0], p[1]), p[2]);
      float a1 = fmaxf(fmaxf(p[3], p[4]), p[5]);
      float a2 = fmaxf(fmaxf(p[6], p[7]), p[8]);
      float a3 = fmaxf(fmaxf(p[9], p[10]), p[11]);
      float a4 = fmaxf(fmaxf(p[12], p[13]), p[14]);
      float tmax = fmaxf(fmaxf(fmaxf(a0, a1), a2), fmaxf(fmaxf(a3, a4), p[15]));
      tmax = fmaxf(tmax, __shfl_xor(tmax, 32));
      if (!__all(tmax <= m)) {
        float newm = fmaxf(m, tmax);
        float scl = __expf(m - newm);
        l *= scl;
#pragma unroll
        for (int r = 0; r < 16; ++r) { zacc[0][r] *= scl; zacc[1][r] *= scl; }
        m = newm;
      }
      float psum = 0.f;
      u32 w[8];
#pragma unroll
      for (int j = 0; j < 8; ++j) {
        float e0 = __expf(p[2 * j] - m);
        float e1 = __expf(p[2 * j + 1] - m);
        psum += e0 + e1;
        w[j] = packbf(e0, e1);
      }
      psum += __shfl_xor(psum, 32);
      l += psum;

      // PV: z^T[d][q] += V^T-frag(A) x P-frag(B) via permlane32_swap word regroup
#pragma unroll
      for (int ktl = 0; ktl < 2; ++ktl) {
        u32 A0 = w[4 * ktl + 0], B0 = w[4 * ktl + 2];
        asm volatile("v_permlane32_swap_b32 %0, %1" : "+v"(A0), "+v"(B0));
        u32 A1 = w[4 * ktl + 1], B1 = w[4 * ktl + 3];
        asm volatile("v_permlane32_swap_b32 %0, %1" : "+v"(A1), "+v"(B1));
        uint4 pw = {A0, A1, B0, B1};
        bf16x8 pf = __builtin_bit_cast(bf16x8, pw);
#pragma unroll
        for (int dh = 0; dh < 2; ++dh) {
          u32 rv = (u32)(dh * 32 + q31);
          u32 L = (rv << 7) + (u32)(kh * 64 + ktl * 32) + (u32)hi * 16u;
          bf16x8 vf = *(const bf16x8*)(Vl + (L ^ ((rv & 7u) << 4)));
          zacc[dh] = __builtin_amdgcn_mfma_f32_32x32x16_bf16(vf, pf, zacc[dh], 0, 0, 0);
        }
      }
    }
    __syncthreads();
    cur ^= 1;
  }

  const int bid = (h * 16 + blockIdx.x) * 3 + blockIdx.z;
  u16* zb = zp + (size_t)bid * 8192 + (size_t)(wv * 32 + q31) * 64;
#pragma unroll
  for (int dh = 0; dh < 2; ++dh)
#pragma unroll
    for (int g = 0; g < 4; ++g) {
      int d0 = dh * 32 + g * 8 + hi * 4;
      uint2 st;
      st.x = packbf(zacc[dh][4 * g + 0], zacc[dh][4 * g + 1]);
      st.y = packbf(zacc[dh][4 * g + 2], zacc[dh][4 * g + 3]);
      *(uint2*)(zb + d0) = st;
    }
  if (hi == 0) mlb[(size_t)bid * 128 + wv * 32 + q31] = make_float2(m, l);
}

// ---------------- split-3 combine ----------------
__global__ __launch_bounds__(256) void comb_kernel(
    const u16* __restrict__ zp, const float2* __restrict__ mlb, u16* __restrict__ zcat)
{
  const int flat = blockIdx.x * 256 + threadIdx.x;   // 524288 total
  const int d4 = flat & 15;
  const int q = (flat >> 4) & 2047;
  const int h = flat >> 15;
  const int qt = q >> 7, qr = q & 127;
  const size_t pb = (size_t)(h * 16 + qt) * 3;
  const size_t base = pb * 8192 + (size_t)qr * 64 + d4 * 4;
  uint2 a = *(const uint2*)(zp + base);
  uint2 b = *(const uint2*)(zp + base + 8192);
  uint2 c = *(const uint2*)(zp + base + 16384);
  float2 ml0 = mlb[pb * 128 + qr];
  float2 ml1 = mlb[(pb + 1) * 128 + qr];
  float2 ml2 = mlb[(pb + 2) * 128 + qr];
  const float M = fmaxf(fmaxf(ml0.x, ml1.x), ml2.x);
  const float e0 = __expf(ml0.x - M), e1 = __expf(ml1.x - M), e2 = __expf(ml2.x - M);
  const float s = 0.125f / (e0 * ml0.y + e1 * ml1.y + e2 * ml2.y);
  float o0 = (e0 * bf2f((u16)(a.x & 0xffff)) + e1 * bf2f((u16)(b.x & 0xffff)) + e2 * bf2f((u16)(c.x & 0xffff))) * s;
  float o1 = (e0 * bf2f((u16)(a.x >> 16))   + e1 * bf2f((u16)(b.x >> 16))   + e2 * bf2f((u16)(c.x >> 16))) * s;
  float o2 = (e0 * bf2f((u16)(a.y & 0xffff)) + e1 * bf2f((u16)(b.y & 0xffff)) + e2 * bf2f((u16)(c.y & 0xffff))) * s;
  float o3 = (e0 * bf2f((u16)(a.y >> 16))   + e1 * bf2f((u16)(b.y >> 16))   + e2 * bf2f((u16)(c.y >> 16))) * s;
  uint2 st;
  st.x = (u32)f2bf(o0) | ((u32)f2bf(o1) << 16);
  st.y = (u32)f2bf(o2) | ((u32)f2bf(o3) << 16);
  *(uint2*)(zcat + (size_t)q * EDIM + h * 64 + d4 * 4) = st;
}

// ---------------- fused split-K reduce + LayerNorm ----------------
__global__ __launch_bounds__(256) void lnred_kernel(
    const float4* __restrict__ pA, const float4* __restrict__ pB,
    const float* __restrict__ bias, const float4* __restrict__ add,
    const float* __restrict__ g, const float* __restrict__ b,
    float* __restrict__ outf, u16* __restrict__ outb)
{
  const int row = blockIdx.x, t = threadIdx.x;
  const int i = row * 256 + t;
  float4 a = pA[i], p2 = pB[i], c = add[i];
  float4 bs = ((const float4*)bias)[t];
  float4 x;
  x.x = a.x + p2.x + c.x + bs.x;
  x.y = a.y + p2.y + c.y + bs.y;
  x.z = a.z + p2.z + c.z + bs.z;
  x.w = a.w + p2.w + c.w + bs.w;
  float s = x.x + x.y + x.z + x.w;
  float sq = x.x * x.x + x.y * x.y + x.z * x.z + x.w * x.w;
#pragma unroll
  for (int msk = 1; msk < 64; msk <<= 1) { s += __shfl_xor(s, msk); sq += __shfl_xor(sq, msk); }
  __shared__ float red[8];
  const int wv = t >> 6, lane = t & 63;
  if (lane == 0) { red[wv] = s; red[4 + wv] = sq; }
  __syncthreads();
  s = red[0] + red[1] + red[2] + red[3];
  sq = red[4] + red[5] + red[6] + red[7];
  const float mu = s * (1.f / EDIM);
  const float rs = rsqrtf(sq * (1.f / EDIM) - mu * mu + 1e-5f);
  float4 gg = ((const float4*)g)[t];
  float4 bb = ((const float4*)b)[t];
  float4 y;
  y.x = (x.x - mu) * rs * gg.x + bb.x;
  y.y = (x.y - mu) * rs * gg.y + bb.y;
  y.z = (x.z - mu) * rs * gg.z + bb.z;
  y.w = (x.w - mu) * rs * gg.w + bb.w;
  if (outf) ((float4*)(outf + (size_t)row * EDIM))[t] = y;
  if (outb) {
    uint2 pkv;
    pkv.x = (u32)f2bf(y.x) | ((u32)f2bf(y.y) << 16);
    pkv.y = (u32)f2bf(y.z) | ((u32)f2bf(y.w) << 16);
    ((uint2*)(outb + (size_t)row * EDIM))[t] = pkv;
  }
}

// ---------------- fused prep: emb | cvt(W0,W1,W2) | wqkv | bias3 in one launch ----------------
__global__ __launch_bounds__(256) void prep_kernel(
    const float4* __restrict__ xw, const float4* __restrict__ xp,
    float4* __restrict__ embf32, uint2* __restrict__ embf16,
    const float4* __restrict__ W0, const float4* __restrict__ W1, const float4* __restrict__ W2,
    uint2* __restrict__ W0b, uint2* __restrict__ W1b, uint2* __restrict__ W2b,
    const float* __restrict__ Wq, const float* __restrict__ Wk, const float* __restrict__ Wv,
    u16* __restrict__ Wqkvt,
    const float* __restrict__ bq, const float* __restrict__ bk, const float* __restrict__ bv,
    float* __restrict__ bias3)
{
  __shared__ float tile[64][65];
  const int b = blockIdx.x, t = threadIdx.x;
  if (b < 2048) {
    const int i = b * 256 + t;
    float4 x = xw[i], y = xp[i];
    float4 e; e.x = x.x + y.x; e.y = x.y + y.y; e.z = x.z + y.z; e.w = x.w + y.w;
    embf32[i] = e;
    uint2 pk;
    pk.x = (u32)f2bf(e.x) | ((u32)f2bf(e.y) << 16);
    pk.y = (u32)f2bf(e.z) | ((u32)f2bf(e.w) << 16);
    embf16[i] = pk;
  } else if (b < 11264) {
    const int i = (b - 2048) * 256 + t;
    float4 x; uint2* dst;
    if (i < 262144) { x = W0[i]; dst = W0b + i; }
    else if (i < 1310720) { int j = i - 262144; x = W1[j]; dst = W1b + j; }
    else { int j = i - 1310720; x = W2[j]; dst = W2b + j; }
    uint2 pk;
    pk.x = (u32)f2bf(x.x) | ((u32)f2bf(x.y) << 16);
    pk.y = (u32)f2bf(x.z) | ((u32)f2bf(x.w) << 16);
    *dst = pk;
  } else if (b < 12032) {
    const int idx = b - 11264;
    const int et = idx & 15, h = (idx >> 4) & 15, wsel = idx >> 8;
    const float* W = wsel == 0 ? Wq : (wsel == 1 ? Wk : Wv);
    const float* src = W + ((size_t)h * EDIM + et * 64) * DDIM;
#pragma unroll
    for (int it = 0; it < 4; ++it) {
      int fi = (t + it * 256) * 4;
      float4 v = *(const float4*)(src + fi);
      int e = fi >> 6, d = fi & 63;
      tile[e][d] = v.x; tile[e][d + 1] = v.y; tile[e][d + 2] = v.z; tile[e][d + 3] = v.w;
    }
    __syncthreads();
    const int d = t >> 2, ec = (t & 3) * 16;
    u16* dst = Wqkvt + ((size_t)(wsel * HNUM + h) * 64 + d) * EDIM + et * 64 + ec;
#pragma unroll
    for (int i = 0; i < 16; i += 2) {
      u32 p = (u32)f2bf(tile[ec + i][d]) | ((u32)f2bf(tile[ec + i + 1][d]) << 16);
      *(u32*)(dst + i) = p;
    }
  } else {
    const int i = (b - 12032) * 256 + t;
    if (i < 3072)
      bias3[i] = i < 1024 ? bq[i] : (i < 2048 ? bk[i - 1024] : bv[i - 2048]);
  }
}

extern "C" void kernel_launch(void* const* d_in, const int* in_sizes, int n_in,
                              void* d_out, int out_size, void* d_ws, size_t ws_size,
                              hipStream_t stream) {
  const float* xw  = (const float*)d_in[0];
  const float* xp  = (const float*)d_in[1];
  const float* Wq  = (const float*)d_in[2];
  const float* bq  = (const float*)d_in[3];
  const float* Wk  = (const float*)d_in[4];
  const float* bk  = (const float*)d_in[5];
  const float* Wv  = (const float*)d_in[6];
  const float* bv  = (const float*)d_in[7];
  const float* W0  = (const float*)d_in[8];
  const float* b0  = (const float*)d_in[9];
  const float* g1  = (const float*)d_in[10];
  const float* be1 = (const float*)d_in[11];
  const float* W1  = (const float*)d_in[12];
  const float* b1  = (const float*)d_in[13];
  const float* W2  = (const float*)d_in[14];
  const float* b2  = (const float*)d_in[15];
  const float* g2  = (const float*)d_in[16];
  const float* be2 = (const float*)d_in[17];
  float* out = (float*)d_out;
  char* ws = (char*)d_ws;

  const size_t MB = 1ull << 20;
  // Lifetime-packed workspace (pairwise audited), peak 64MB + 12KB:
  float* embf32 = (float*)(ws + 0);          // prep -> lnred1           0..8
  u16*   embf16 = (u16*)(ws + 8 * MB);       // prep -> QKVgemm          8..12
  u16*   zcat   = (u16*)(ws + 8 * MB);       // comb -> W0gemm           8..12 (embf16 dead)
  u16*   out1b  = (u16*)(ws + 8 * MB);       // lnred1 -> W1gemm         8..12 (zcat dead)
  u16*   Wqkvt  = (u16*)(ws + 12 * MB);      // prep -> QKVgemm          12..18
  float2* mlb   = (float2*)(ws + 12 * MB);   // attn -> comb             12..12.75 (Wqkvt dead)
  u16*   h1     = (u16*)(ws + 12 * MB);      // W1gemm -> W2gemm         12..28
  u16*   QKV    = (u16*)(ws + 18 * MB);      // QKVgemm -> attn          18..30 (Q,K only)
  float* w0pA   = (float*)(ws + 18 * MB);    // W0gemm -> lnred1         18..26 (QKV dead)
  float* w0pB   = (float*)(ws + 26 * MB);    // W0gemm -> lnred1         26..34
  u16*   Vt     = (u16*)(ws + 30 * MB);      // QKVgemm -> attn          30..34
  u16*   zp     = (u16*)(ws + 34 * MB);      // attn -> comb             34..46 (12MB)
  float* out1f  = (float*)(ws + 34 * MB);    // lnred1 -> lnred2         34..42 (zp dead)
  u16*   W0b    = (u16*)(ws + 46 * MB);      // prep -> W0gemm           46..48
  u16*   W1b    = (u16*)(ws + 48 * MB);      // prep -> W1gemm           48..56
  u16*   W2b    = (u16*)(ws + 56 * MB);      // prep -> W2gemm           56..64
  float* w2pA   = (float*)(ws + 0);          // W2gemm -> lnred2         0..8  (embf32 dead)
  float* w2pB   = (float*)(ws + 42 * MB);    // W2gemm -> lnred2         42..50 (zp/W0b/W1b-head dead)
  float* bias3  = (float*)(ws + 64 * MB);    // 12KB

  // fused prep (1 launch, replaces emb + 3x cvt + bias3 + wqkv)
  prep_kernel<<<12044, 256, 0, stream>>>(
      (const float4*)xw, (const float4*)xp, (float4*)embf32, (uint2*)embf16,
      (const float4*)W0, (const float4*)W1, (const float4*)W2,
      (uint2*)W0b, (uint2*)W1b, (uint2*)W2b,
      Wq, Wk, Wv, Wqkvt, bq, bk, bv, bias3);

  // QKV projection (768 blocks = 3/CU); V columns stored transposed to Vt directly
  gemm_bt64<0><<<dim3(3072 / 128, 2048 / 64, 1), 256, 0, stream>>>(
      embf16, Wqkvt, bias3, nullptr, QKV, Vt, SLEN, 3072, 1024, 1024);

  // flash attention 32x32, KV-split-3 (768 blocks = 3/CU)
  attn_kernel<<<dim3(SLEN / 128, HNUM, 3), 256, 0, stream>>>(QKV, Vt, zp, mlb);
  comb_kernel<<<2048, 256, 0, stream>>>(zp, mlb, zcat);

  // W0 proj, split-K=2 -> partials; lnred1 adds b0 + emb residual and does LN1
  gemm_bt64<3><<<dim3(1024 / 128, 2048 / 64, 2), 256, 0, stream>>>(
      zcat, W0b, nullptr, w0pB, w0pA, nullptr, SLEN, 1024, 1024, 512);
  lnred_kernel<<<SLEN, 256, 0, stream>>>((const float4*)w0pA, (const float4*)w0pB,
                                         b0, (const float4*)embf32, g1, be1, out1f, out1b);

  // FFN up + relu -> h1 (64x128 tiles: 1024 blocks = 4/CU, was 128^2 at 2/CU)
  gemm_bt64<1><<<dim3(4096 / 128, 2048 / 64, 1), 256, 0, stream>>>(
      out1b, W1b, b1, nullptr, h1, nullptr, SLEN, 4096, 1024, 1024);

  // FFN down, split-K=2 -> partials; lnred2 adds b2 + out1 residual and does LN2 -> out
  gemm_bt64<3><<<dim3(1024 / 128, 2048 / 64, 2), 256, 0, stream>>>(
      h1, W2b, nullptr, w2pB, w2pA, nullptr, SLEN, 1024, 4096, 2048);
  lnred_kernel<<<SLEN, 256, 0, stream>>>((const float4*)w2pA, (const float4*)w2pB,
                                         b2, (const float4*)out1f, g2, be2, out, nullptr);
}

// Round 13
// 159.539 us; speedup vs baseline: 1.0256x; 1.0256x over previous
//
#include <hip/hip_runtime.h>

#define SLEN 2048
#define EDIM 1024
#define HNUM 16
#define DDIM 64

typedef unsigned short u16;
typedef unsigned int u32;
typedef __attribute__((ext_vector_type(8))) __bf16 bf16x8;
typedef __attribute__((ext_vector_type(2))) __bf16 bf16x2;
typedef __attribute__((ext_vector_type(4))) float f32x4;
typedef __attribute__((ext_vector_type(16))) float f32x16;

__device__ __forceinline__ u16 f2bf(float f) {
  u32 u = __builtin_bit_cast(u32, f);
  u = (u + 0x7fffu + ((u >> 16) & 1u)) >> 16;
  return (u16)u;
}

__device__ __forceinline__ float bf2f(u16 v) {
  u32 u = ((u32)v) << 16;
  return __builtin_bit_cast(float, u);
}

__device__ __forceinline__ u32 packbf(float a, float b) {
  bf16x2 t; t[0] = (__bf16)a; t[1] = (__bf16)b;
  return __builtin_bit_cast(u32, t);
}

__device__ __forceinline__ void gload_lds16(const void* g, void* l) {
  __builtin_amdgcn_global_load_lds(
      (const __attribute__((address_space(1))) void*)g,
      (__attribute__((address_space(3))) void*)l, 16, 0, 0);
}

// XOR swizzle for 128B-row LDS tiles
__device__ __forceinline__ u32 swz(u32 b) { return b ^ (((b >> 7) & 7u) << 4); }

// ---------------- GEMM 128x128 tile (R7-proven 2-barrier structure) ----------------
// MODE 0: bf16=acc+bias ; MODE 1: bf16=relu(acc+bias) ; MODE 2: f32=acc+bias+add
template<int MODE>
__global__ __launch_bounds__(256, 2) void gemm_bt(
    const u16* __restrict__ A, const u16* __restrict__ Bt,
    const float* __restrict__ bias, const float* __restrict__ add,
    void* __restrict__ outp, int M, int N, int K)
{
  __shared__ __align__(16) u16 As[128 * 64];
  __shared__ __align__(16) u16 Bs[128 * 64];
  const int t = threadIdx.x;
  const int lane = t & 63, wv = t >> 6;
  const int bm = blockIdx.y * 128, bn = blockIdx.x * 128;
  const int wm = (wv >> 1) * 64, wn = (wv & 1) * 64;
  f32x4 acc[4][4] = {};

  const char* Ab = (const char*)A;
  const char* Bb = (const char*)Bt;

  for (int k0 = 0; k0 < K; k0 += 64) {
    __syncthreads();
#pragma unroll
    for (int j = 0; j < 4; ++j) {
      u32 bp = (u32)t * 16u + (u32)j * 4096u;
      u32 L = swz(bp);
      u32 row = L >> 7, colb = L & 127u;
      gload_lds16(Ab + ((size_t)(bm + row) * K + k0) * 2 + colb, (char*)As + bp);
      gload_lds16(Bb + ((size_t)(bn + row) * K + k0) * 2 + colb, (char*)Bs + bp);
    }
    __syncthreads();
#pragma unroll
    for (int ks = 0; ks < 2; ++ks) {
      bf16x8 af[4], bfr[4];
#pragma unroll
      for (int i = 0; i < 4; ++i) {
        u32 ra = (u32)(wm + i * 16 + (lane & 15));
        u32 La = (ra << 7) + (u32)ks * 64u + (u32)(lane >> 4) * 16u;
        af[i] = *(const bf16x8*)((const char*)As + (La ^ ((ra & 7u) << 4)));
        u32 rb = (u32)(wn + i * 16 + (lane & 15));
        u32 Lb = (rb << 7) + (u32)ks * 64u + (u32)(lane >> 4) * 16u;
        bfr[i] = *(const bf16x8*)((const char*)Bs + (Lb ^ ((rb & 7u) << 4)));
      }
#pragma unroll
      for (int mi = 0; mi < 4; ++mi)
#pragma unroll
        for (int ni = 0; ni < 4; ++ni)
          acc[mi][ni] = __builtin_amdgcn_mfma_f32_16x16x32_bf16(af[mi], bfr[ni], acc[mi][ni], 0, 0, 0);
    }
  }

  const int cr = (lane >> 4) * 4, cc = lane & 15;
#pragma unroll
  for (int ni = 0; ni < 4; ++ni) {
    const int col = bn + wn + ni * 16 + cc;
    const float bvv = bias[col];
#pragma unroll
    for (int mi = 0; mi < 4; ++mi) {
#pragma unroll
      for (int r = 0; r < 4; ++r) {
        const int row = bm + wm + mi * 16 + cr + r;
        float v = acc[mi][ni][r] + bvv;
        const size_t idx = (size_t)row * N + col;
        if constexpr (MODE == 0) ((u16*)outp)[idx] = f2bf(v);
        else if constexpr (MODE == 1) ((u16*)outp)[idx] = f2bf(v > 0.f ? v : 0.f);
        else ((float*)outp)[idx] = v + add[idx];
      }
    }
  }
}

// ---------------- GEMM 64x128 tile, split-K, fused V-transpose ----------------
// MODE 0: bf16=acc+bias; if vtp && col>=2048, store transposed to vtp instead of outp.
// MODE 3: f32 partial (no bias), z=0 -> outp, z=1 -> part1
template<int MODE>
__global__ __launch_bounds__(256, 4) void gemm_bt64(
    const u16* __restrict__ A, const u16* __restrict__ Bt,
    const float* __restrict__ bias, float* __restrict__ part1,
    void* __restrict__ outp, u16* __restrict__ vtp, int M, int N, int lda, int KS)
{
  __shared__ __align__(16) u16 As[64 * 64];    // 8KB
  __shared__ __align__(16) u16 Bs[128 * 64];   // 16KB
  const int t = threadIdx.x;
  const int lane = t & 63, wv = t >> 6;
  const int bm = blockIdx.y * 64, bn = blockIdx.x * 128;
  const int wm = (wv >> 1) * 32, wn = (wv & 1) * 64;
  const int koff = blockIdx.z * KS;
  f32x4 acc[2][4] = {};

  const char* Ab = (const char*)A;
  const char* Bb = (const char*)Bt;

  for (int k0 = koff; k0 < koff + KS; k0 += 64) {
    __syncthreads();
    {
      u32 bp = (u32)t * 16u;
      u32 L = swz(bp);
      u32 row = L >> 7, colb = L & 127u;
      gload_lds16(Ab + ((size_t)(bm + row) * lda + k0) * 2 + colb, (char*)As + bp);
      u32 bp2 = bp + 4096u;
      u32 L2 = swz(bp2);
      u32 row2 = L2 >> 7, colb2 = L2 & 127u;
      gload_lds16(Ab + ((size_t)(bm + row2) * lda + k0) * 2 + colb2, (char*)As + bp2);
    }
#pragma unroll
    for (int j = 0; j < 4; ++j) {
      u32 bp = (u32)t * 16u + (u32)j * 4096u;
      u32 L = swz(bp);
      u32 row = L >> 7, colb = L & 127u;
      gload_lds16(Bb + ((size_t)(bn + row) * lda + k0) * 2 + colb, (char*)Bs + bp);
    }
    __syncthreads();
#pragma unroll
    for (int ks = 0; ks < 2; ++ks) {
      bf16x8 af[2], bfr[4];
#pragma unroll
      for (int i = 0; i < 2; ++i) {
        u32 ra = (u32)(wm + i * 16 + (lane & 15));
        u32 La = (ra << 7) + (u32)ks * 64u + (u32)(lane >> 4) * 16u;
        af[i] = *(const bf16x8*)((const char*)As + (La ^ ((ra & 7u) << 4)));
      }
#pragma unroll
      for (int i = 0; i < 4; ++i) {
        u32 rb = (u32)(wn + i * 16 + (lane & 15));
        u32 Lb = (rb << 7) + (u32)ks * 64u + (u32)(lane >> 4) * 16u;
        bfr[i] = *(const bf16x8*)((const char*)Bs + (Lb ^ ((rb & 7u) << 4)));
      }
#pragma unroll
      for (int mi = 0; mi < 2; ++mi)
#pragma unroll
        for (int ni = 0; ni < 4; ++ni)
          acc[mi][ni] = __builtin_amdgcn_mfma_f32_16x16x32_bf16(af[mi], bfr[ni], acc[mi][ni], 0, 0, 0);
    }
  }

  float* po = (MODE == 3 && blockIdx.z) ? part1 : (float*)outp;
  const int cr = (lane >> 4) * 4, cc = lane & 15;
#pragma unroll
  for (int ni = 0; ni < 4; ++ni) {
    const int colb0 = bn + wn + ni * 16;   // wave-uniform
    const int col = colb0 + cc;
    if (MODE == 0 && vtp != nullptr && colb0 >= 2048) {
      // V columns: store transposed Vt[col-2048][row0..row0+3] (8B aligned)
      const float bvv = bias[col];
      const int vcol = col - 2048;
#pragma unroll
      for (int mi = 0; mi < 2; ++mi) {
        const int row0 = bm + wm + mi * 16 + cr;
        uint2 st;
        st.x = packbf(acc[mi][ni][0] + bvv, acc[mi][ni][1] + bvv);
        st.y = packbf(acc[mi][ni][2] + bvv, acc[mi][ni][3] + bvv);
        *(uint2*)(vtp + (size_t)vcol * SLEN + row0) = st;
      }
    } else {
      const float bvv = (MODE == 3) ? 0.f : bias[col];
#pragma unroll
      for (int mi = 0; mi < 2; ++mi) {
#pragma unroll
        for (int r = 0; r < 4; ++r) {
          const int row = bm + wm + mi * 16 + cr + r;
          float v = acc[mi][ni][r] + bvv;
          const size_t idx = (size_t)row * N + col;
          if constexpr (MODE == 0) ((u16*)outp)[idx] = f2bf(v);
          else if constexpr (MODE == 1) ((u16*)outp)[idx] = f2bf(v > 0.f ? v : 0.f);
          else po[idx] = v;
        }
      }
    }
  }
}

// ---------------- flash attention, 32x32 MFMA, KV-split-3 (R9-proven) ----------------
// Block (qt, h, z): q-rows qt*128..+127 (4 waves x 32), keys: z<2 ? 768 : 512.
// Partials: zp bf16 [bid][128 q][64 d], mlb float2 [bid][128 q]; bid=(h*16+qt)*3+z.
__global__ __launch_bounds__(256, 4) void attn_kernel(
    const u16* __restrict__ qkv, const u16* __restrict__ vt,
    u16* __restrict__ zp, float2* __restrict__ mlb)
{
  __shared__ __align__(16) char lds[32768];  // 2 bufs x (K 8KB + Vt 8KB)
  const int t = threadIdx.x, lane = t & 63;
  const int q31 = lane & 31, hi = lane >> 5;
  const int wv = t >> 6;
  const int h = blockIdx.y;
  const int qrow = blockIdx.x * 128 + wv * 32 + q31;
  const int kt0 = blockIdx.z * 12;
  const int cnt = (blockIdx.z == 2) ? 8 : 12;

  bf16x8 qf[4];
#pragma unroll
  for (int ds = 0; ds < 4; ++ds)
    qf[ds] = *(const bf16x8*)(qkv + (size_t)qrow * 3072 + h * 64 + ds * 16 + hi * 8);

  const char* kgp[2];
  const char* vgp[2];
  u32 ldo[2];
#pragma unroll
  for (int j = 0; j < 2; ++j) {
    u32 bp = (u32)t * 16u + (u32)j * 4096u;
    u32 L = swz(bp);
    u32 row = L >> 7, colb = L & 127u;
    kgp[j] = (const char*)qkv + ((size_t)row * 3072 + 1024 + h * 64) * 2 + colb;
    vgp[j] = (const char*)vt + ((size_t)(h * 64 + row)) * (SLEN * 2) + colb;
    ldo[j] = bp;
  }

  f32x16 zacc[2] = {};   // zacc[dh][reg] = z^T[32*dh + (reg&3)+8*(reg>>2)+4*hi][q31]
  float m = -1e30f, l = 0.f;

  {
    size_t ko = (size_t)kt0 * (64 * 3072 * 2);
    int vo = kt0 * 128;
#pragma unroll
    for (int j = 0; j < 2; ++j) {
      gload_lds16(kgp[j] + ko, lds + ldo[j]);
      gload_lds16(vgp[j] + vo, lds + 8192 + ldo[j]);
    }
  }
  __syncthreads();

  int cur = 0;
  for (int it = 0; it < cnt; ++it) {
    const int kt = kt0 + it;
    if (it + 1 < cnt) {
      char* base = lds + (cur ^ 1) * 16384;
      size_t ko = (size_t)(kt + 1) * (64 * 3072 * 2);
      int vo = (kt + 1) * 128;
#pragma unroll
      for (int j = 0; j < 2; ++j) {
        gload_lds16(kgp[j] + ko, base + ldo[j]);
        gload_lds16(vgp[j] + vo, base + 8192 + ldo[j]);
      }
    }

    const char* Kl = lds + cur * 16384;
    const char* Vl = Kl + 8192;

#pragma unroll
    for (int kh = 0; kh < 2; ++kh) {
      // QK^T swapped: P[kc][q], kc = kh*32 + (reg&3)+8*(reg>>2)+4*hi, q = q31
      f32x16 p = {};
#pragma unroll
      for (int ds = 0; ds < 4; ++ds) {
        u32 rk = (u32)(kh * 32 + q31);
        u32 L = (rk << 7) + (u32)ds * 32u + (u32)hi * 16u;
        bf16x8 kf = *(const bf16x8*)(Kl + (L ^ ((rk & 7u) << 4)));
        p = __builtin_amdgcn_mfma_f32_32x32x16_bf16(kf, qf[ds], p, 0, 0, 0);
      }

      // online softmax (defer-max); max reduce as v_max3 tree
      float a0 = fmaxf(fmaxf(p[0], p[1]), p[2]);
      float a1 = fmaxf(fmaxf(p[3], p[4]), p[5]);
      float a2 = fmaxf(fmaxf(p[6], p[7]), p[8]);
      float a3 = fmaxf(fmaxf(p[9], p[10]), p[11]);
      float a4 = fmaxf(fmaxf(p[12], p[13]), p[14]);
      float tmax = fmaxf(fmaxf(fmaxf(a0, a1), a2), fmaxf(fmaxf(a3, a4), p[15]));
      tmax = fmaxf(tmax, __shfl_xor(tmax, 32));
      if (!__all(tmax <= m)) {
        float newm = fmaxf(m, tmax);
        float scl = __expf(m - newm);
        l *= scl;
#pragma unroll
        for (int r = 0; r < 16; ++r) { zacc[0][r] *= scl; zacc[1][r] *= scl; }
        m = newm;
      }
      float psum = 0.f;
      u32 w[8];
#pragma unroll
      for (int j = 0; j < 8; ++j) {
        float e0 = __expf(p[2 * j] - m);
        float e1 = __expf(p[2 * j + 1] - m);
        psum += e0 + e1;
        w[j] = packbf(e0, e1);
      }
      psum += __shfl_xor(psum, 32);
      l += psum;

      // PV: z^T[d][q] += V^T-frag(A) x P-frag(B) via permlane32_swap word regroup
#pragma unroll
      for (int ktl = 0; ktl < 2; ++ktl) {
        u32 A0 = w[4 * ktl + 0], B0 = w[4 * ktl + 2];
        asm volatile("v_permlane32_swap_b32 %0, %1" : "+v"(A0), "+v"(B0));
        u32 A1 = w[4 * ktl + 1], B1 = w[4 * ktl + 3];
        asm volatile("v_permlane32_swap_b32 %0, %1" : "+v"(A1), "+v"(B1));
        uint4 pw = {A0, A1, B0, B1};
        bf16x8 pf = __builtin_bit_cast(bf16x8, pw);
#pragma unroll
        for (int dh = 0; dh < 2; ++dh) {
          u32 rv = (u32)(dh * 32 + q31);
          u32 L = (rv << 7) + (u32)(kh * 64 + ktl * 32) + (u32)hi * 16u;
          bf16x8 vf = *(const bf16x8*)(Vl + (L ^ ((rv & 7u) << 4)));
          zacc[dh] = __builtin_amdgcn_mfma_f32_32x32x16_bf16(vf, pf, zacc[dh], 0, 0, 0);
        }
      }
    }
    __syncthreads();
    cur ^= 1;
  }

  const int bid = (h * 16 + blockIdx.x) * 3 + blockIdx.z;
  u16* zb = zp + (size_t)bid * 8192 + (size_t)(wv * 32 + q31) * 64;
#pragma unroll
  for (int dh = 0; dh < 2; ++dh)
#pragma unroll
    for (int g = 0; g < 4; ++g) {
      int d0 = dh * 32 + g * 8 + hi * 4;
      uint2 st;
      st.x = packbf(zacc[dh][4 * g + 0], zacc[dh][4 * g + 1]);
      st.y = packbf(zacc[dh][4 * g + 2], zacc[dh][4 * g + 3]);
      *(uint2*)(zb + d0) = st;
    }
  if (hi == 0) mlb[(size_t)bid * 128 + wv * 32 + q31] = make_float2(m, l);
}

// ---------------- split-3 combine ----------------
__global__ __launch_bounds__(256) void comb_kernel(
    const u16* __restrict__ zp, const float2* __restrict__ mlb, u16* __restrict__ zcat)
{
  const int flat = blockIdx.x * 256 + threadIdx.x;   // 524288 total
  const int d4 = flat & 15;
  const int q = (flat >> 4) & 2047;
  const int h = flat >> 15;
  const int qt = q >> 7, qr = q & 127;
  const size_t pb = (size_t)(h * 16 + qt) * 3;
  const size_t base = pb * 8192 + (size_t)qr * 64 + d4 * 4;
  uint2 a = *(const uint2*)(zp + base);
  uint2 b = *(const uint2*)(zp + base + 8192);
  uint2 c = *(const uint2*)(zp + base + 16384);
  float2 ml0 = mlb[pb * 128 + qr];
  float2 ml1 = mlb[(pb + 1) * 128 + qr];
  float2 ml2 = mlb[(pb + 2) * 128 + qr];
  const float M = fmaxf(fmaxf(ml0.x, ml1.x), ml2.x);
  const float e0 = __expf(ml0.x - M), e1 = __expf(ml1.x - M), e2 = __expf(ml2.x - M);
  const float s = 0.125f / (e0 * ml0.y + e1 * ml1.y + e2 * ml2.y);
  float o0 = (e0 * bf2f((u16)(a.x & 0xffff)) + e1 * bf2f((u16)(b.x & 0xffff)) + e2 * bf2f((u16)(c.x & 0xffff))) * s;
  float o1 = (e0 * bf2f((u16)(a.x >> 16))   + e1 * bf2f((u16)(b.x >> 16))   + e2 * bf2f((u16)(c.x >> 16))) * s;
  float o2 = (e0 * bf2f((u16)(a.y & 0xffff)) + e1 * bf2f((u16)(b.y & 0xffff)) + e2 * bf2f((u16)(c.y & 0xffff))) * s;
  float o3 = (e0 * bf2f((u16)(a.y >> 16))   + e1 * bf2f((u16)(b.y >> 16))   + e2 * bf2f((u16)(c.y >> 16))) * s;
  uint2 st;
  st.x = (u32)f2bf(o0) | ((u32)f2bf(o1) << 16);
  st.y = (u32)f2bf(o2) | ((u32)f2bf(o3) << 16);
  *(uint2*)(zcat + (size_t)q * EDIM + h * 64 + d4 * 4) = st;
}

// ---------------- fused split-K reduce + LayerNorm ----------------
__global__ __launch_bounds__(256) void lnred_kernel(
    const float4* __restrict__ pA, const float4* __restrict__ pB,
    const float* __restrict__ bias, const float4* __restrict__ add,
    const float* __restrict__ g, const float* __restrict__ b,
    float* __restrict__ outf, u16* __restrict__ outb)
{
  const int row = blockIdx.x, t = threadIdx.x;
  const int i = row * 256 + t;
  float4 a = pA[i], p2 = pB[i], c = add[i];
  float4 bs = ((const float4*)bias)[t];
  float4 x;
  x.x = a.x + p2.x + c.x + bs.x;
  x.y = a.y + p2.y + c.y + bs.y;
  x.z = a.z + p2.z + c.z + bs.z;
  x.w = a.w + p2.w + c.w + bs.w;
  float s = x.x + x.y + x.z + x.w;
  float sq = x.x * x.x + x.y * x.y + x.z * x.z + x.w * x.w;
#pragma unroll
  for (int msk = 1; msk < 64; msk <<= 1) { s += __shfl_xor(s, msk); sq += __shfl_xor(sq, msk); }
  __shared__ float red[8];
  const int wv = t >> 6, lane = t & 63;
  if (lane == 0) { red[wv] = s; red[4 + wv] = sq; }
  __syncthreads();
  s = red[0] + red[1] + red[2] + red[3];
  sq = red[4] + red[5] + red[6] + red[7];
  const float mu = s * (1.f / EDIM);
  const float rs = rsqrtf(sq * (1.f / EDIM) - mu * mu + 1e-5f);
  float4 gg = ((const float4*)g)[t];
  float4 bb = ((const float4*)b)[t];
  float4 y;
  y.x = (x.x - mu) * rs * gg.x + bb.x;
  y.y = (x.y - mu) * rs * gg.y + bb.y;
  y.z = (x.z - mu) * rs * gg.z + bb.z;
  y.w = (x.w - mu) * rs * gg.w + bb.w;
  if (outf) ((float4*)(outf + (size_t)row * EDIM))[t] = y;
  if (outb) {
    uint2 pkv;
    pkv.x = (u32)f2bf(y.x) | ((u32)f2bf(y.y) << 16);
    pkv.y = (u32)f2bf(y.z) | ((u32)f2bf(y.w) << 16);
    ((uint2*)(outb + (size_t)row * EDIM))[t] = pkv;
  }
}

// ---------------- fused prep: emb | cvt(W0,W1,W2) | wqkv | bias3 in one launch ----------------
__global__ __launch_bounds__(256) void prep_kernel(
    const float4* __restrict__ xw, const float4* __restrict__ xp,
    float4* __restrict__ embf32, uint2* __restrict__ embf16,
    const float4* __restrict__ W0, const float4* __restrict__ W1, const float4* __restrict__ W2,
    uint2* __restrict__ W0b, uint2* __restrict__ W1b, uint2* __restrict__ W2b,
    const float* __restrict__ Wq, const float* __restrict__ Wk, const float* __restrict__ Wv,
    u16* __restrict__ Wqkvt,
    const float* __restrict__ bq, const float* __restrict__ bk, const float* __restrict__ bv,
    float* __restrict__ bias3)
{
  __shared__ float tile[64][65];
  const int b = blockIdx.x, t = threadIdx.x;
  if (b < 2048) {
    const int i = b * 256 + t;
    float4 x = xw[i], y = xp[i];
    float4 e; e.x = x.x + y.x; e.y = x.y + y.y; e.z = x.z + y.z; e.w = x.w + y.w;
    embf32[i] = e;
    uint2 pk;
    pk.x = (u32)f2bf(e.x) | ((u32)f2bf(e.y) << 16);
    pk.y = (u32)f2bf(e.z) | ((u32)f2bf(e.w) << 16);
    embf16[i] = pk;
  } else if (b < 11264) {
    const int i = (b - 2048) * 256 + t;
    float4 x; uint2* dst;
    if (i < 262144) { x = W0[i]; dst = W0b + i; }
    else if (i < 1310720) { int j = i - 262144; x = W1[j]; dst = W1b + j; }
    else { int j = i - 1310720; x = W2[j]; dst = W2b + j; }
    uint2 pk;
    pk.x = (u32)f2bf(x.x) | ((u32)f2bf(x.y) << 16);
    pk.y = (u32)f2bf(x.z) | ((u32)f2bf(x.w) << 16);
    *dst = pk;
  } else if (b < 12032) {
    const int idx = b - 11264;
    const int et = idx & 15, h = (idx >> 4) & 15, wsel = idx >> 8;
    const float* W = wsel == 0 ? Wq : (wsel == 1 ? Wk : Wv);
    const float* src = W + ((size_t)h * EDIM + et * 64) * DDIM;
#pragma unroll
    for (int it = 0; it < 4; ++it) {
      int fi = (t + it * 256) * 4;
      float4 v = *(const float4*)(src + fi);
      int e = fi >> 6, d = fi & 63;
      tile[e][d] = v.x; tile[e][d + 1] = v.y; tile[e][d + 2] = v.z; tile[e][d + 3] = v.w;
    }
    __syncthreads();
    const int d = t >> 2, ec = (t & 3) * 16;
    u16* dst = Wqkvt + ((size_t)(wsel * HNUM + h) * 64 + d) * EDIM + et * 64 + ec;
#pragma unroll
    for (int i = 0; i < 16; i += 2) {
      u32 p = (u32)f2bf(tile[ec + i][d]) | ((u32)f2bf(tile[ec + i + 1][d]) << 16);
      *(u32*)(dst + i) = p;
    }
  } else {
    const int i = (b - 12032) * 256 + t;
    if (i < 3072)
      bias3[i] = i < 1024 ? bq[i] : (i < 2048 ? bk[i - 1024] : bv[i - 2048]);
  }
}

extern "C" void kernel_launch(void* const* d_in, const int* in_sizes, int n_in,
                              void* d_out, int out_size, void* d_ws, size_t ws_size,
                              hipStream_t stream) {
  const float* xw  = (const float*)d_in[0];
  const float* xp  = (const float*)d_in[1];
  const float* Wq  = (const float*)d_in[2];
  const float* bq  = (const float*)d_in[3];
  const float* Wk  = (const float*)d_in[4];
  const float* bk  = (const float*)d_in[5];
  const float* Wv  = (const float*)d_in[6];
  const float* bv  = (const float*)d_in[7];
  const float* W0  = (const float*)d_in[8];
  const float* b0  = (const float*)d_in[9];
  const float* g1  = (const float*)d_in[10];
  const float* be1 = (const float*)d_in[11];
  const float* W1  = (const float*)d_in[12];
  const float* b1  = (const float*)d_in[13];
  const float* W2  = (const float*)d_in[14];
  const float* b2  = (const float*)d_in[15];
  const float* g2  = (const float*)d_in[16];
  const float* be2 = (const float*)d_in[17];
  float* out = (float*)d_out;
  char* ws = (char*)d_ws;

  const size_t MB = 1ull << 20;
  // Lifetime-packed workspace (pairwise audited), peak 64MB + 12KB:
  float* embf32 = (float*)(ws + 0);          // prep -> lnred1           0..8
  u16*   embf16 = (u16*)(ws + 8 * MB);       // prep -> QKVgemm          8..12
  u16*   zcat   = (u16*)(ws + 8 * MB);       // comb -> W0gemm           8..12 (embf16 dead)
  u16*   out1b  = (u16*)(ws + 8 * MB);       // lnred1 -> W1gemm         8..12 (zcat dead)
  u16*   Wqkvt  = (u16*)(ws + 12 * MB);      // prep -> QKVgemm          12..18
  float2* mlb   = (float2*)(ws + 12 * MB);   // attn -> comb             12..12.75 (Wqkvt dead)
  u16*   h1     = (u16*)(ws + 12 * MB);      // W1gemm -> W2gemm         12..28
  u16*   QKV    = (u16*)(ws + 18 * MB);      // QKVgemm -> attn          18..30 (Q,K only)
  float* w0pA   = (float*)(ws + 18 * MB);    // W0gemm -> lnred1         18..26 (QKV dead)
  float* w0pB   = (float*)(ws + 26 * MB);    // W0gemm -> lnred1         26..34
  u16*   Vt     = (u16*)(ws + 30 * MB);      // QKVgemm -> attn          30..34
  u16*   zp     = (u16*)(ws + 34 * MB);      // attn -> comb             34..46 (12MB)
  float* out1f  = (float*)(ws + 34 * MB);    // lnred1 -> lnred2         34..42 (zp dead)
  u16*   W0b    = (u16*)(ws + 46 * MB);      // prep -> W0gemm           46..48
  u16*   W1b    = (u16*)(ws + 48 * MB);      // prep -> W1gemm           48..56
  u16*   W2b    = (u16*)(ws + 56 * MB);      // prep -> W2gemm           56..64
  float* w2pA   = (float*)(ws + 0);          // W2gemm -> lnred2         0..8  (embf32 dead)
  float* w2pB   = (float*)(ws + 42 * MB);    // W2gemm -> lnred2         42..50 (zp/W0b/W1b-head dead)
  float* bias3  = (float*)(ws + 64 * MB);    // 12KB

  // fused prep (1 launch, replaces emb + 3x cvt + bias3 + wqkv)
  prep_kernel<<<12044, 256, 0, stream>>>(
      (const float4*)xw, (const float4*)xp, (float4*)embf32, (uint2*)embf16,
      (const float4*)W0, (const float4*)W1, (const float4*)W2,
      (uint2*)W0b, (uint2*)W1b, (uint2*)W2b,
      Wq, Wk, Wv, Wqkvt, bq, bk, bv, bias3);

  // QKV projection (768 blocks = 3/CU); V columns stored transposed to Vt directly
  gemm_bt64<0><<<dim3(3072 / 128, 2048 / 64, 1), 256, 0, stream>>>(
      embf16, Wqkvt, bias3, nullptr, QKV, Vt, SLEN, 3072, 1024, 1024);

  // flash attention 32x32, KV-split-3 (768 blocks = 3/CU)
  attn_kernel<<<dim3(SLEN / 128, HNUM, 3), 256, 0, stream>>>(QKV, Vt, zp, mlb);
  comb_kernel<<<2048, 256, 0, stream>>>(zp, mlb, zcat);

  // W0 proj, split-K=2 -> partials; lnred1 adds b0 + emb residual and does LN1
  gemm_bt64<3><<<dim3(1024 / 128, 2048 / 64, 2), 256, 0, stream>>>(
      zcat, W0b, nullptr, w0pB, w0pA, nullptr, SLEN, 1024, 1024, 512);
  lnred_kernel<<<SLEN, 256, 0, stream>>>((const float4*)w0pA, (const float4*)w0pB,
                                         b0, (const float4*)embf32, g1, be1, out1f, out1b);

  // FFN up + relu -> h1 (128^2 tiles: 512 blocks = 2/CU; R11-proven best)
  gemm_bt<1><<<dim3(4096 / 128, 2048 / 128), 256, 0, stream>>>(
      out1b, W1b, b1, nullptr, h1, SLEN, 4096, 1024);

  // FFN down, split-K=2 -> partials; lnred2 adds b2 + out1 residual and does LN2 -> out
  gemm_bt64<3><<<dim3(1024 / 128, 2048 / 64, 2), 256, 0, stream>>>(
      h1, W2b, nullptr, w2pB, w2pA, nullptr, SLEN, 1024, 4096, 2048);
  lnred_kernel<<<SLEN, 256, 0, stream>>>((const float4*)w2pA, (const float4*)w2pB,
                                         b2, (const float4*)out1f, g2, be2, out, nullptr);
}